// Round 16
// baseline (256.802 us; speedup 1.0000x reference)
//
#include <hip/hip_runtime.h>
#include <hip/hip_bf16.h>
#include <math.h>

// AttentionLayer: B=16, T=2048, D=256
// out[b,d,s] = h[b,s,d] + sum_t h[b,t,d] * softmax_s(m[b,t,:] @ aw[b,:,:]^T)[s]
//   h = in[...,0:256] + in[...,256:512]; m = tanh(h); aw = relu(h @ W^T + b)
// Pipeline (fp16 intermediates) — r15 + k2z s-split for 4 blocks/CU:
//   kA: prep, FULL-LINE nt stores -> h16, m16, hfrag
//   kB: aw GEMM; epilogue transposes through LDS -> full-line nt stores
//   k2z: grid (32 tt, 2 s-half, 16 b) = 1024 blocks -> 4/CU. Single-buffer awch 33.8KB,
//        reg-prefetched staging, 2 LDS-only barriers per 64-s step (16 steps).
//        Z partials -> d_out scratch; kRed sums the 2 halves (deterministic).
//   k3o: cooperative exp, h-frag prefetch, S-prefetch, MFMA PV with setprio.
// Frag layouts:
//   Sfrag[b][s/16][t/32][lane][8]: value(s,t) at lane=(s&15)+16*((t&31)>>3), j=t&7
//   hfrag[b][d/16][t/32][lane][8]: same mapping with d in place of s
// h16 aliases the first 16MB of the Sfrag region. Zpart aliases d_out (dead until k3o).
// r8: NT full-line only. r11: keep per-step barriers. r15: Sfrag through-cache (L3).

#define NB 16
#define NT 2048
#define ND 256

typedef __attribute__((ext_vector_type(4))) float f32x4;
typedef __attribute__((ext_vector_type(8))) short s16x8;
typedef __attribute__((ext_vector_type(4))) short s16x4;
typedef __attribute__((ext_vector_type(8))) _Float16 f16x8;
typedef unsigned short u16;

__device__ __forceinline__ u16 f2h(float x) {
  union { _Float16 h; u16 u; } v; v.h = (_Float16)x; return v.u;
}
__device__ __forceinline__ float h2f(u16 u) {
  union { u16 u; _Float16 h; } v; v.u = u; return (float)v.h;
}
__device__ __forceinline__ float tanh_fast(float x) {
  return 1.f - 2.f / (1.f + __expf(2.f * x));  // exact at tails, branch-free
}
// LDS-only barrier: waits ds ops (lgkmcnt) but NOT global/NT traffic (vmcnt floats).
__device__ __forceinline__ void ldsbar() {
  __builtin_amdgcn_sched_barrier(0);
  asm volatile("s_waitcnt lgkmcnt(0)" ::: "memory");
  __builtin_amdgcn_s_barrier();
  __builtin_amdgcn_sched_barrier(0);
}

// ---------------- kA: h = a+b; h16 [t][d], m16 [t][d], hfrag [d/16][t/32][lane][8] ----------------
__global__ __launch_bounds__(256, 8) void kA(const float* __restrict__ inF,
    u16* __restrict__ h16, u16* __restrict__ m16, u16* __restrict__ hfrag)
{
  __shared__ __attribute__((aligned(16))) u16 hld[32][264];   // [t][d] fp16 h
  const int blk = blockIdx.x;
  const int b   = blk >> 6;           // 64 blocks per batch
  const int t0  = (blk & 63) << 5;    // 32 rows
  const int tid = threadIdx.x;
  const int w    = tid >> 6;
  const int lane = tid & 63;
  const int rh   = lane >> 5;          // 0/1
  const int dseg = (lane & 31) << 3;   // 0..248 step 8
  #pragma unroll
  for (int it = 0; it < 4; ++it) {
    const int rloc = w * 8 + it * 2 + rh;
    const size_t grow = (size_t)(b * NT + t0 + rloc);
    const float* base = inF + grow * (2 * ND) + dseg;
    float4 a0 = *(const float4*)(base);
    float4 a1 = *(const float4*)(base + 4);
    float4 c0 = *(const float4*)(base + ND);
    float4 c1 = *(const float4*)(base + ND + 4);
    float hv[8] = {a0.x + c0.x, a0.y + c0.y, a0.z + c0.z, a0.w + c0.w,
                   a1.x + c1.x, a1.y + c1.y, a1.z + c1.z, a1.w + c1.w};
    s16x8 vh, vm;
    #pragma unroll
    for (int r = 0; r < 8; ++r) {
      vh[r] = (short)f2h(hv[r]);
      vm[r] = (short)f2h(tanh_fast(hv[r]));
    }
    *(s16x8*)&hld[rloc][dseg] = vh;
    __builtin_nontemporal_store(vh, (s16x8*)(h16 + grow * ND + dseg));
    __builtin_nontemporal_store(vm, (s16x8*)(m16 + grow * ND + dseg));
  }
  ldsbar();   // hld ready; NT stores keep flowing
  u16* Hb = hfrag + (size_t)b * ND * NT;
  const int ti = t0 >> 5;
  #pragma unroll
  for (int s = 0; s < 4; ++s) {
    const int slot  = tid * 4 + s;
    const int dtile = slot >> 6;
    const int lp    = slot & 63;
    const int d  = dtile * 16 + (lp & 15);
    const int tb = (lp >> 4) * 8;
    s16x8 v;
    #pragma unroll
    for (int j = 0; j < 8; ++j) v[j] = (short)hld[tb + j][d];
    __builtin_nontemporal_store(v,
        (s16x8*)(Hb + (((size_t)dtile * (NT / 32) + ti) * 64 + lp) * 8));
  }
}

// ---------------- kB: aw = relu(h @ W^T + b); LDS-transposed full-line nt stores ----------------
__global__ __launch_bounds__(256, 2) void kB(const u16* __restrict__ h16,
    const float* __restrict__ W, const float* __restrict__ bias, u16* __restrict__ aw16)
{
  __shared__ __attribute__((aligned(16))) u16 Wl[128][264];
  const int r0 = blockIdx.x << 7;
  const int e0 = blockIdx.y << 7;
  const int tid = threadIdx.x;
  #pragma unroll
  for (int rep = 0; rep < 16; ++rep) {
    const int idx = rep * 2048 + tid * 8;
    const int er = idx >> 8, col = idx & 255;
    float4 x0 = *(const float4*)(W + (size_t)(e0 + er) * ND + col);
    float4 x1 = *(const float4*)(W + (size_t)(e0 + er) * ND + col + 4);
    s16x8 v;
    v[0] = (short)f2h(x0.x); v[1] = (short)f2h(x0.y); v[2] = (short)f2h(x0.z); v[3] = (short)f2h(x0.w);
    v[4] = (short)f2h(x1.x); v[5] = (short)f2h(x1.y); v[6] = (short)f2h(x1.z); v[7] = (short)f2h(x1.w);
    *(s16x8*)&Wl[er][col] = v;
  }
  const int lane = tid & 63;
  const int w    = tid >> 6;
  const int l15  = lane & 15, kg = lane >> 4;
  float bv[8];
  #pragma unroll
  for (int et = 0; et < 8; ++et) bv[et] = bias[e0 + et * 16 + l15];
  f32x4 acc[2][8];
  #pragma unroll
  for (int rt = 0; rt < 2; ++rt)
    #pragma unroll
    for (int et = 0; et < 8; ++et) acc[rt][et] = (f32x4){0.f, 0.f, 0.f, 0.f};
  ldsbar();
  #pragma unroll
  for (int ks = 0; ks < 8; ++ks) {
    f16x8 af[2];
    #pragma unroll
    for (int rt = 0; rt < 2; ++rt)
      af[rt] = *(const f16x8*)(h16 + (size_t)(r0 + w * 32 + rt * 16 + l15) * ND + ks * 32 + kg * 8);
    #pragma unroll
    for (int et = 0; et < 8; ++et) {
      f16x8 bf = *(const f16x8*)&Wl[et * 16 + l15][ks * 32 + kg * 8];
      #pragma unroll
      for (int rt = 0; rt < 2; ++rt)
        acc[rt][et] = __builtin_amdgcn_mfma_f32_16x16x32_f16(af[rt], bf, acc[rt][et], 0, 0, 0);
    }
  }
  ldsbar();   // all waves done reading Wl
  u16 (*awt)[132] = (u16 (*)[132])(&Wl[0][0]);   // 128x132x2B = 33.8KB
  #pragma unroll
  for (int rt = 0; rt < 2; ++rt)
    #pragma unroll
    for (int et = 0; et < 8; ++et) {
      const int e_loc = et * 16 + l15;
      #pragma unroll
      for (int r = 0; r < 4; ++r) {
        const int row_loc = w * 32 + rt * 16 + kg * 4 + r;
        float v = acc[rt][et][r] + bv[et];
        awt[row_loc][e_loc] = f2h(v > 0.f ? v : 0.f);
      }
    }
  ldsbar();
  #pragma unroll
  for (int it = 0; it < 8; ++it) {
    const int rloc = it * 16 + w * 4 + (lane >> 4);
    const int sb   = (lane & 15) << 3;
    s16x8 v = *(const s16x8*)&awt[rloc][sb];
    __builtin_nontemporal_store(v, (s16x8*)(aw16 + (size_t)(r0 + rloc) * ND + e0 + sb));
  }
}

// ---------------- k2z: s-split (grid 1024, 4 blocks/CU). Sfrag + Z-partials ----------------
__global__ __launch_bounds__(512, 8) void k2z(
    const u16* __restrict__ m16, const u16* __restrict__ aw16,
    u16* __restrict__ Sfrag, float* __restrict__ Zpart)
{
  __shared__ __attribute__((aligned(16))) u16 awch[64][264];  // 33.8 KB single buffer
  __shared__ float zp[2][64];
  const int tt  = blockIdx.x;        // t-tile of 64 (0..31)
  const int sh  = blockIdx.y;        // s-half (0..1)
  const int b   = blockIdx.z;        // batch
  const int t0  = tt << 6;
  const int tid = threadIdx.x;
  const int lane = tid & 63;
  const int w    = tid >> 6;         // 0..7
  const int grp  = w >> 2;           // s 32-row half within 64-s step
  const int wl   = w & 3;            // t-row owner (16 rows each)
  const int l15 = lane & 15, kg = lane >> 4;
  f16x8 afr[8];
  const size_t abase = ((size_t)(b * NT + t0 + wl * 16 + l15)) * ND + kg * 8;
  #pragma unroll
  for (int ks = 0; ks < 8; ++ks) afr[ks] = *(const f16x8*)(m16 + abase + ks * 32);
  const u16* awb = aw16 + (size_t)b * NT * ND;
  u16* STb = Sfrag + (size_t)b * NT * NT;
  const int ti    = tt * 2 + (wl >> 1);
  const int lanep = l15 + 16 * ((wl & 1) * 2 + (kg >> 1));
  const int jp    = (kg & 1) * 4;
  // reg-prefetched staging: loads issued one full step ahead of the LDS write.
  s16x8 rg[4];
  auto loadReg = [&](int step) {
    const int s0 = sh * (NT / 2) + (step << 6);
    #pragma unroll
    for (int rep = 0; rep < 4; ++rep) {
      const int idx = rep * 4096 + tid * 8;
      rg[rep] = *(const s16x8*)(awb + (size_t)(s0 + (idx >> 8)) * ND + (idx & 255));
    }
  };
  auto writeReg = [&]() {
    #pragma unroll
    for (int rep = 0; rep < 4; ++rep) {
      const int idx = rep * 4096 + tid * 8;
      *(s16x8*)&awch[idx >> 8][idx & 255] = rg[rep];
    }
  };
  loadReg(0);
  float zacc[4] = {0.f, 0.f, 0.f, 0.f};
  for (int step = 0; step < 16; ++step) {
    ldsbar();                       // prior step's awch reads drained (no-op at step 0)
    writeReg();                     // vmcnt wait hits loads issued a full step ago
    if (step < 15) loadReg(step + 1);
    ldsbar();                       // stage visible to all waves
    f32x4 accS[2];
    accS[0] = (f32x4){0.f, 0.f, 0.f, 0.f};
    accS[1] = (f32x4){0.f, 0.f, 0.f, 0.f};
    __builtin_amdgcn_s_setprio(1);
    #pragma unroll
    for (int ks = 0; ks < 8; ++ks) {
      #pragma unroll
      for (int st = 0; st < 2; ++st) {
        f16x8 bf = *(const f16x8*)&awch[grp * 32 + st * 16 + l15][ks * 32 + kg * 8];
        accS[st] = __builtin_amdgcn_mfma_f32_16x16x32_f16(afr[ks], bf, accS[st], 0, 0, 0);
      }
    }
    __builtin_amdgcn_s_setprio(0);
    #pragma unroll
    for (int st = 0; st < 2; ++st) {
      const int si = sh * 64 + step * 4 + grp * 2 + st;   // s/16 index
      s16x4 sv;
      #pragma unroll
      for (int r = 0; r < 4; ++r) sv[r] = (short)f2h(accS[st][r]);
      *(s16x4*)(STb + (((size_t)si * 64 + ti) * 64 + lanep) * 8 + jp) = sv;  // through-cache
      #pragma unroll
      for (int r = 0; r < 4; ++r) zacc[r] += __expf(accS[st][r]);
    }
  }
  ldsbar();
  #pragma unroll
  for (int r = 0; r < 4; ++r) {
    #pragma unroll
    for (int o = 1; o < 16; o <<= 1) zacc[r] += __shfl_xor(zacc[r], o, 64);
  }
  if (l15 == 0) {
    #pragma unroll
    for (int r = 0; r < 4; ++r) zp[grp][wl * 16 + kg * 4 + r] = zacc[r];
  }
  ldsbar();
  if (tid < 64)
    Zpart[((size_t)b * 2 + sh) * NT + t0 + tid] = zp[0][tid] + zp[1][tid];
}

// ---------------- kRed: Zarr[b][t] = Zpart[b][0][t] + Zpart[b][1][t] (fixed order) ----------------
__global__ __launch_bounds__(256) void kRed(const float* __restrict__ Zpart,
    float* __restrict__ Zarr)
{
  const int b = blockIdx.y;
  const int t = blockIdx.x * 256 + threadIdx.x;   // grid.x = 8
  Zarr[(size_t)b * NT + t] = Zpart[((size_t)b * 2 + 0) * NT + t]
                           + Zpart[((size_t)b * 2 + 1) * NT + t];
}

// ---------------- k3o: cooperative exp + PV GEMM, h-frag prefetch. out = h^T + O^T ----------------
__global__ __launch_bounds__(512, 4) void k3o(
    const u16* __restrict__ Sfrag, const u16* __restrict__ hfrag,
    const float* __restrict__ Zarr, float* __restrict__ outp)
{
  __shared__ __attribute__((aligned(16))) u16 Pbuf[2][4][2][64][8];  // [buf][st][ks][lane][8]
  __shared__ float zld[NT];                                          // 1/Z
  const int b   = blockIdx.y;
  const int s0t = blockIdx.x;          // s-tile of 64 (0..31)
  const int tid = threadIdx.x;
  const int lane = tid & 63;
  const int w    = tid >> 6;           // 0..7; owns d-slice [w*32, +32)
  const int l15 = lane & 15, kg = lane >> 4;
  const u16* Sb = Sfrag + (size_t)b * NT * NT;
  const u16* Hb = hfrag + (size_t)b * ND * NT;
  {
    float4 z = *(const float4*)(Zarr + (size_t)b * NT + tid * 4);
    zld[tid * 4 + 0] = 1.f / z.x;
    zld[tid * 4 + 1] = 1.f / z.y;
    zld[tid * 4 + 2] = 1.f / z.z;
    zld[tid * 4 + 3] = 1.f / z.w;
  }
  const int mst = w >> 1, mks = w & 1;   // this wave's exp duty: sub-frag (st=mst, ks=mks)
  const u16* sp = Sb + ((((size_t)(s0t * 4 + mst)) * 64 + mks) * 64 + lane) * 8;
  auto loadS = [&](int ch) -> s16x8 {
    return *(const s16x8*)(sp + (size_t)ch * 1024);   // regular: can hit L3
  };
  auto expP = [&](s16x8 v, int ch) -> s16x8 {
    const float* rzp = &zld[(ch * 2 + mks) * 32 + kg * 8];
    float4 ra = *(const float4*)rzp;
    float4 rb = *(const float4*)(rzp + 4);
    const float rv[8] = {ra.x, ra.y, ra.z, ra.w, rb.x, rb.y, rb.z, rb.w};
    s16x8 p;
    #pragma unroll
    for (int j = 0; j < 8; ++j) p[j] = (short)f2h(__expf(h2f((u16)v[j])) * rv[j]);
    return p;
  };
  auto loadH = [&](f16x8 (&dst)[2][2], int ch) {
    #pragma unroll
    for (int dt = 0; dt < 2; ++dt)
      #pragma unroll
      for (int ks = 0; ks < 2; ++ks)
        dst[dt][ks] = *(const f16x8*)(Hb + (((size_t)(w * 2 + dt) * 64 + ch * 2 + ks) * 64 + lane) * 8);
  };

  f32x4 acc[4][2];
  #pragma unroll
  for (int st = 0; st < 4; ++st) {
    acc[st][0] = (f32x4){0.f, 0.f, 0.f, 0.f};
    acc[st][1] = (f32x4){0.f, 0.f, 0.f, 0.f};
  }
  auto mfmaStep = [&](int cur, f16x8 (&hb)[2][2]) {
    __builtin_amdgcn_s_setprio(1);
    #pragma unroll
    for (int ks = 0; ks < 2; ++ks) {
      f16x8 pa[4];
      #pragma unroll
      for (int st = 0; st < 4; ++st)
        pa[st] = *(const f16x8*)&Pbuf[cur][st][ks][lane][0];
      #pragma unroll
      for (int dt = 0; dt < 2; ++dt)
        #pragma unroll
        for (int st = 0; st < 4; ++st)
          acc[st][dt] = __builtin_amdgcn_mfma_f32_16x16x32_f16(pa[st], hb[dt][ks], acc[st][dt], 0, 0, 0);
    }
    __builtin_amdgcn_s_setprio(0);
  };

  s16x8 d0 = loadS(0);
  s16x8 d1 = loadS(1);
  s16x8 d2 = loadS(2);
  f16x8 hA[2][2], hB[2][2];
  loadH(hA, 0);
  ldsbar();                             // zld ready
  {
    s16x8 pr = expP(d0, 0);
    *(s16x8*)&Pbuf[0][mst][mks][lane][0] = pr;
  }
  ldsbar();                             // Pbuf[0] ready

  for (int ch = 0; ch < 32; ch += 2) {
    // ---- even chunk ch (reads Pbuf[0], hA) ----
    loadH(hB, ch + 1);
    {
      s16x8 prn = expP(d1, ch + 1);     // d1 holds chunk ch+1
      d1 = d2;
      if (ch + 3 < 32) d2 = loadS(ch + 3);
      mfmaStep(0, hA);
      *(s16x8*)&Pbuf[1][mst][mks][lane][0] = prn;
    }
    ldsbar();
    // ---- odd chunk ch+1 (reads Pbuf[1], hB) ----
    if (ch + 2 < 32) loadH(hA, ch + 2);
    const bool wr = (ch + 2 < 32);
    s16x8 prn2;
    if (wr) prn2 = expP(d1, ch + 2);    // d1 holds chunk ch+2
    d1 = d2;
    if (ch + 4 < 32) d2 = loadS(ch + 4);
    mfmaStep(1, hB);
    if (wr) *(s16x8*)&Pbuf[0][mst][mks][lane][0] = prn2;
    ldsbar();
  }
  // epilogue: out[b][d][s] = h[d][s] + O[s][d]; residual h from hfrag
  #pragma unroll
  for (int st = 0; st < 4; ++st) {
    const int sb = s0t * 64 + st * 16 + kg * 4;
    #pragma unroll
    for (int dt = 0; dt < 2; ++dt) {
      const int d = w * 32 + dt * 16 + l15;
      const u16* hres = Hb + (((size_t)(w * 2 + dt) * 64 + (s0t * 2 + (st >> 1))) * 64
                        + (l15 + 16 * ((st & 1) * 2 + (kg >> 1)))) * 8 + (kg & 1) * 4;
      float4 o;
      o.x = acc[st][dt][0] + h2f(hres[0]);
      o.y = acc[st][dt][1] + h2f(hres[1]);
      o.z = acc[st][dt][2] + h2f(hres[2]);
      o.w = acc[st][dt][3] + h2f(hres[3]);
      *(float4*)(outp + ((size_t)(b * ND + d)) * NT + sb) = o;
    }
  }
}

extern "C" void kernel_launch(void* const* d_in, const int* in_sizes, int n_in,
                              void* d_out, int out_size, void* d_ws, size_t ws_size,
                              hipStream_t stream) {
  const float* inF  = (const float*)d_in[0];  // [16][2048][512]
  const float* W    = (const float*)d_in[1];  // [256][256]
  const float* bias = (const float*)d_in[2];  // [256]
  float* outp = (float*)d_out;                // [16][256][2048]

  const size_t SZ = (size_t)NB * NT * ND;     // 8,388,608 elems
  u16* m16   = (u16*)d_ws;
  u16* hfrag = m16 + SZ;
  u16* aw16  = hfrag + SZ;
  float* Zarr = (float*)(aw16 + SZ);          // [B][NT] fp32 Z
  u16* Sfrag = (u16*)(Zarr + (size_t)NB * NT); // fp16 fragment-tiled S, 128 MiB
  u16* h16   = Sfrag;                          // alias: dead after kB, overwritten by k2z
  float* Zpart = outp;                         // [B][2][NT] f32 scratch in d_out (256 KB)
  const size_t need = 3 * SZ * sizeof(u16) + (size_t)NB * NT * sizeof(float)
                    + (size_t)NB * NT * NT * sizeof(u16);   // proven present
  if (ws_size < need) return;  // visible failure (output stays poisoned)

  kA  <<<dim3(NB * NT / 32), dim3(256), 0, stream>>>(inF, h16, m16, hfrag);
  kB  <<<dim3(256, 2), dim3(256), 0, stream>>>(h16, W, bias, aw16);
  k2z <<<dim3(32, 2, NB), dim3(512), 0, stream>>>(m16, aw16, Sfrag, Zpart);
  kRed<<<dim3(NT / 256, NB), dim3(256), 0, stream>>>(Zpart, Zarr);
  k3o <<<dim3(NT / 64, NB), dim3(512), 0, stream>>>(Sfrag, hfrag, Zarr, outp);
}

// Round 18
// 168.255 us; speedup vs baseline: 1.5263x; 1.5263x over previous
//
#include <hip/hip_runtime.h>
#include <hip/hip_bf16.h>
#include <math.h>

// AttentionLayer: B=16, T=2048, D=256
// out[b,d,s] = h[b,s,d] + sum_t h[b,t,d] * softmax_s(m[b,t,:] @ aw[b,:,:]^T)[s]
//   h = in[...,0:256] + in[...,256:512]; m = tanh(h); aw = relu(h @ W^T + b)
// Pipeline (fp16 intermediates) — exact r15 (best: 170.3us) + NT out-stores in k3o:
//   kA: prep, FULL-LINE nt stores -> h16, m16, hfrag
//   kB: aw GEMM; epilogue transposes through LDS -> full-line nt stores
//   k2z: S = m @ aw^T -> Sfrag (through-cache -> L3-resident for k3o) + Z; reg-staged,
//        LDS-only barriers, setprio. Grid 512 (2 blocks/CU): the per-step barrier
//        lockstep IS the cache-sweep alignment (r11/r16: breaking it = 3-5x FETCH).
//   k3o: cooperative exp, h-frag prefetch (hA/hB), S-prefetch 3-deep, setprio MFMA,
//        residual epilogue with NT full-line out stores (kills out-RFO).
// Frag layouts:
//   Sfrag[b][s/16][t/32][lane][8]: value(s,t) at lane=(s&15)+16*((t&31)>>3), j=t&7
//   hfrag[b][d/16][t/32][lane][8]: same mapping with d in place of s
// h16 aliases the first 16MB of the Sfrag region (dead after kB, overwritten by k2z).
// Refuted levers (keep away): barrier removal (r11), k2z occupancy x2 (r10,r16),
// NT partial-line stores (r8), LDS-redundancy retile (r14).
// NOTE: __builtin_nontemporal_store needs ext_vector types, not HIP float4 (r17 compile fix).

#define NB 16
#define NT 2048
#define ND 256

typedef __attribute__((ext_vector_type(4))) float f32x4;
typedef __attribute__((ext_vector_type(8))) short s16x8;
typedef __attribute__((ext_vector_type(4))) short s16x4;
typedef __attribute__((ext_vector_type(8))) _Float16 f16x8;
typedef unsigned short u16;

__device__ __forceinline__ u16 f2h(float x) {
  union { _Float16 h; u16 u; } v; v.h = (_Float16)x; return v.u;
}
__device__ __forceinline__ float h2f(u16 u) {
  union { u16 u; _Float16 h; } v; v.u = u; return (float)v.h;
}
__device__ __forceinline__ float tanh_fast(float x) {
  return 1.f - 2.f / (1.f + __expf(2.f * x));  // exact at tails, branch-free
}
// LDS-only barrier: waits ds ops (lgkmcnt) but NOT global/NT traffic (vmcnt floats).
__device__ __forceinline__ void ldsbar() {
  __builtin_amdgcn_sched_barrier(0);
  asm volatile("s_waitcnt lgkmcnt(0)" ::: "memory");
  __builtin_amdgcn_s_barrier();
  __builtin_amdgcn_sched_barrier(0);
}

// ---------------- kA: h = a+b; h16 [t][d], m16 [t][d], hfrag [d/16][t/32][lane][8] ----------------
__global__ __launch_bounds__(256, 8) void kA(const float* __restrict__ inF,
    u16* __restrict__ h16, u16* __restrict__ m16, u16* __restrict__ hfrag)
{
  __shared__ __attribute__((aligned(16))) u16 hld[32][264];   // [t][d] fp16 h
  const int blk = blockIdx.x;
  const int b   = blk >> 6;           // 64 blocks per batch
  const int t0  = (blk & 63) << 5;    // 32 rows
  const int tid = threadIdx.x;
  const int w    = tid >> 6;
  const int lane = tid & 63;
  const int rh   = lane >> 5;          // 0/1
  const int dseg = (lane & 31) << 3;   // 0..248 step 8
  #pragma unroll
  for (int it = 0; it < 4; ++it) {
    const int rloc = w * 8 + it * 2 + rh;
    const size_t grow = (size_t)(b * NT + t0 + rloc);
    const float* base = inF + grow * (2 * ND) + dseg;
    float4 a0 = *(const float4*)(base);
    float4 a1 = *(const float4*)(base + 4);
    float4 c0 = *(const float4*)(base + ND);
    float4 c1 = *(const float4*)(base + ND + 4);
    float hv[8] = {a0.x + c0.x, a0.y + c0.y, a0.z + c0.z, a0.w + c0.w,
                   a1.x + c1.x, a1.y + c1.y, a1.z + c1.z, a1.w + c1.w};
    s16x8 vh, vm;
    #pragma unroll
    for (int r = 0; r < 8; ++r) {
      vh[r] = (short)f2h(hv[r]);
      vm[r] = (short)f2h(tanh_fast(hv[r]));
    }
    *(s16x8*)&hld[rloc][dseg] = vh;
    __builtin_nontemporal_store(vh, (s16x8*)(h16 + grow * ND + dseg));
    __builtin_nontemporal_store(vm, (s16x8*)(m16 + grow * ND + dseg));
  }
  ldsbar();   // hld ready; NT stores keep flowing
  u16* Hb = hfrag + (size_t)b * ND * NT;
  const int ti = t0 >> 5;
  #pragma unroll
  for (int s = 0; s < 4; ++s) {
    const int slot  = tid * 4 + s;
    const int dtile = slot >> 6;
    const int lp    = slot & 63;
    const int d  = dtile * 16 + (lp & 15);
    const int tb = (lp >> 4) * 8;
    s16x8 v;
    #pragma unroll
    for (int j = 0; j < 8; ++j) v[j] = (short)hld[tb + j][d];
    __builtin_nontemporal_store(v,
        (s16x8*)(Hb + (((size_t)dtile * (NT / 32) + ti) * 64 + lp) * 8));
  }
}

// ---------------- kB: aw = relu(h @ W^T + b); LDS-transposed full-line nt stores ----------------
__global__ __launch_bounds__(256, 2) void kB(const u16* __restrict__ h16,
    const float* __restrict__ W, const float* __restrict__ bias, u16* __restrict__ aw16)
{
  __shared__ __attribute__((aligned(16))) u16 Wl[128][264];
  const int r0 = blockIdx.x << 7;
  const int e0 = blockIdx.y << 7;
  const int tid = threadIdx.x;
  #pragma unroll
  for (int rep = 0; rep < 16; ++rep) {
    const int idx = rep * 2048 + tid * 8;
    const int er = idx >> 8, col = idx & 255;
    float4 x0 = *(const float4*)(W + (size_t)(e0 + er) * ND + col);
    float4 x1 = *(const float4*)(W + (size_t)(e0 + er) * ND + col + 4);
    s16x8 v;
    v[0] = (short)f2h(x0.x); v[1] = (short)f2h(x0.y); v[2] = (short)f2h(x0.z); v[3] = (short)f2h(x0.w);
    v[4] = (short)f2h(x1.x); v[5] = (short)f2h(x1.y); v[6] = (short)f2h(x1.z); v[7] = (short)f2h(x1.w);
    *(s16x8*)&Wl[er][col] = v;
  }
  const int lane = tid & 63;
  const int w    = tid >> 6;
  const int l15  = lane & 15, kg = lane >> 4;
  float bv[8];
  #pragma unroll
  for (int et = 0; et < 8; ++et) bv[et] = bias[e0 + et * 16 + l15];
  f32x4 acc[2][8];
  #pragma unroll
  for (int rt = 0; rt < 2; ++rt)
    #pragma unroll
    for (int et = 0; et < 8; ++et) acc[rt][et] = (f32x4){0.f, 0.f, 0.f, 0.f};
  ldsbar();
  #pragma unroll
  for (int ks = 0; ks < 8; ++ks) {
    f16x8 af[2];
    #pragma unroll
    for (int rt = 0; rt < 2; ++rt)
      af[rt] = *(const f16x8*)(h16 + (size_t)(r0 + w * 32 + rt * 16 + l15) * ND + ks * 32 + kg * 8);
    #pragma unroll
    for (int et = 0; et < 8; ++et) {
      f16x8 bf = *(const f16x8*)&Wl[et * 16 + l15][ks * 32 + kg * 8];
      #pragma unroll
      for (int rt = 0; rt < 2; ++rt)
        acc[rt][et] = __builtin_amdgcn_mfma_f32_16x16x32_f16(af[rt], bf, acc[rt][et], 0, 0, 0);
    }
  }
  ldsbar();   // all waves done reading Wl
  u16 (*awt)[132] = (u16 (*)[132])(&Wl[0][0]);   // 128x132x2B = 33.8KB
  #pragma unroll
  for (int rt = 0; rt < 2; ++rt)
    #pragma unroll
    for (int et = 0; et < 8; ++et) {
      const int e_loc = et * 16 + l15;
      #pragma unroll
      for (int r = 0; r < 4; ++r) {
        const int row_loc = w * 32 + rt * 16 + kg * 4 + r;
        float v = acc[rt][et][r] + bv[et];
        awt[row_loc][e_loc] = f2h(v > 0.f ? v : 0.f);
      }
    }
  ldsbar();
  #pragma unroll
  for (int it = 0; it < 8; ++it) {
    const int rloc = it * 16 + w * 4 + (lane >> 4);
    const int sb   = (lane & 15) << 3;
    s16x8 v = *(const s16x8*)&awt[rloc][sb];
    __builtin_nontemporal_store(v, (s16x8*)(aw16 + (size_t)(r0 + rloc) * ND + e0 + sb));
  }
}

// ---------------- k2z: Sfrag (through-cache) + Z[b][t]; reg-staged, LDS barriers ----------------
__global__ __launch_bounds__(512, 4) void k2z(
    const u16* __restrict__ m16, const u16* __restrict__ aw16,
    u16* __restrict__ Sfrag, float* __restrict__ Zarr)
{
  __shared__ __attribute__((aligned(16))) u16 awch[2][64][264];  // 67.6 KB
  __shared__ float zp[2][64];
  const int tt  = blockIdx.x;        // t-tile of 64 (0..31)
  const int b   = blockIdx.y;
  const int t0  = tt << 6;
  const int tid = threadIdx.x;
  const int lane = tid & 63;
  const int w    = tid >> 6;         // 0..7
  const int grp  = w >> 2;           // s 32-row half within chunk
  const int wl   = w & 3;            // t-row owner (16 rows each)
  const int l15 = lane & 15, kg = lane >> 4;
  f16x8 afr[8];
  const size_t abase = ((size_t)(b * NT + t0 + wl * 16 + l15)) * ND + kg * 8;
  #pragma unroll
  for (int ks = 0; ks < 8; ++ks) afr[ks] = *(const f16x8*)(m16 + abase + ks * 32);
  const u16* awb = aw16 + (size_t)b * NT * ND;
  u16* STb = Sfrag + (size_t)b * NT * NT;
  const int ti    = tt * 2 + (wl >> 1);
  const int lanep = l15 + 16 * ((wl & 1) * 2 + (kg >> 1));
  const int jp    = (kg & 1) * 4;
  // T14 staging: loads issued 2 steps ahead, LDS writes at step start.
  s16x8 rg[4];
  auto loadReg = [&](int step) {
    const int s0 = step << 6;
    #pragma unroll
    for (int rep = 0; rep < 4; ++rep) {
      const int idx = rep * 4096 + tid * 8;
      rg[rep] = *(const s16x8*)(awb + (size_t)(s0 + (idx >> 8)) * ND + (idx & 255));
    }
  };
  auto writeReg = [&](int buf) {
    #pragma unroll
    for (int rep = 0; rep < 4; ++rep) {
      const int idx = rep * 4096 + tid * 8;
      *(s16x8*)&awch[buf][idx >> 8][idx & 255] = rg[rep];
    }
  };
  loadReg(0); writeReg(0);     // step 0 (latency exposed once)
  loadReg(1);                  // step 1 in flight
  float zacc[4] = {0.f, 0.f, 0.f, 0.f};
  ldsbar();
  for (int step = 0; step < 32; ++step) {
    const int c = step & 1;
    if (step < 31) writeReg(c ^ 1);    // regs(step+1) -> other buffer (barrier'd)
    if (step < 30) loadReg(step + 2);  // issue next loads (full step to land)
    f32x4 accS[2];
    accS[0] = (f32x4){0.f, 0.f, 0.f, 0.f};
    accS[1] = (f32x4){0.f, 0.f, 0.f, 0.f};
    __builtin_amdgcn_s_setprio(1);
    #pragma unroll
    for (int ks = 0; ks < 8; ++ks) {
      #pragma unroll
      for (int st = 0; st < 2; ++st) {
        f16x8 bf = *(const f16x8*)&awch[c][grp * 32 + st * 16 + l15][ks * 32 + kg * 8];
        accS[st] = __builtin_amdgcn_mfma_f32_16x16x32_f16(afr[ks], bf, accS[st], 0, 0, 0);
      }
    }
    __builtin_amdgcn_s_setprio(0);
    #pragma unroll
    for (int st = 0; st < 2; ++st) {
      const int si = step * 4 + grp * 2 + st;
      s16x4 sv;
      #pragma unroll
      for (int r = 0; r < 4; ++r) sv[r] = (short)f2h(accS[st][r]);
      *(s16x4*)(STb + (((size_t)si * 64 + ti) * 64 + lanep) * 8 + jp) = sv;  // through-cache
      #pragma unroll
      for (int r = 0; r < 4; ++r) zacc[r] += __expf(accS[st][r]);
    }
    ldsbar();
  }
  #pragma unroll
  for (int r = 0; r < 4; ++r) {
    #pragma unroll
    for (int o = 1; o < 16; o <<= 1) zacc[r] += __shfl_xor(zacc[r], o, 64);
  }
  if (l15 == 0) {
    #pragma unroll
    for (int r = 0; r < 4; ++r) zp[grp][wl * 16 + kg * 4 + r] = zacc[r];
  }
  ldsbar();
  if (tid < 64)
    Zarr[(size_t)b * NT + t0 + tid] = zp[0][tid] + zp[1][tid];
}

// ---------------- k3o: cooperative exp + PV GEMM, h-frag prefetch. out = h^T + O^T ----------------
__global__ __launch_bounds__(512, 4) void k3o(
    const u16* __restrict__ Sfrag, const u16* __restrict__ hfrag,
    const float* __restrict__ Zarr, float* __restrict__ outp)
{
  __shared__ __attribute__((aligned(16))) u16 Pbuf[2][4][2][64][8];  // [buf][st][ks][lane][8]
  __shared__ float zld[NT];                                          // 1/Z
  const int b   = blockIdx.y;
  const int s0t = blockIdx.x;          // s-tile of 64 (0..31)
  const int tid = threadIdx.x;
  const int lane = tid & 63;
  const int w    = tid >> 6;           // 0..7; owns d-slice [w*32, +32)
  const int l15 = lane & 15, kg = lane >> 4;
  const u16* Sb = Sfrag + (size_t)b * NT * NT;
  const u16* Hb = hfrag + (size_t)b * ND * NT;
  {
    float4 z = *(const float4*)(Zarr + (size_t)b * NT + tid * 4);
    zld[tid * 4 + 0] = 1.f / z.x;
    zld[tid * 4 + 1] = 1.f / z.y;
    zld[tid * 4 + 2] = 1.f / z.z;
    zld[tid * 4 + 3] = 1.f / z.w;
  }
  const int mst = w >> 1, mks = w & 1;   // this wave's exp duty: sub-frag (st=mst, ks=mks)
  const u16* sp = Sb + ((((size_t)(s0t * 4 + mst)) * 64 + mks) * 64 + lane) * 8;
  auto loadS = [&](int ch) -> s16x8 {
    return *(const s16x8*)(sp + (size_t)ch * 1024);   // regular: can hit L3
  };
  auto expP = [&](s16x8 v, int ch) -> s16x8 {
    const float* rzp = &zld[(ch * 2 + mks) * 32 + kg * 8];
    float4 ra = *(const float4*)rzp;
    float4 rb = *(const float4*)(rzp + 4);
    const float rv[8] = {ra.x, ra.y, ra.z, ra.w, rb.x, rb.y, rb.z, rb.w};
    s16x8 p;
    #pragma unroll
    for (int j = 0; j < 8; ++j) p[j] = (short)f2h(__expf(h2f((u16)v[j])) * rv[j]);
    return p;
  };
  auto loadH = [&](f16x8 (&dst)[2][2], int ch) {
    #pragma unroll
    for (int dt = 0; dt < 2; ++dt)
      #pragma unroll
      for (int ks = 0; ks < 2; ++ks)
        dst[dt][ks] = *(const f16x8*)(Hb + (((size_t)(w * 2 + dt) * 64 + ch * 2 + ks) * 64 + lane) * 8);
  };

  f32x4 acc[4][2];
  #pragma unroll
  for (int st = 0; st < 4; ++st) {
    acc[st][0] = (f32x4){0.f, 0.f, 0.f, 0.f};
    acc[st][1] = (f32x4){0.f, 0.f, 0.f, 0.f};
  }
  auto mfmaStep = [&](int cur, f16x8 (&hb)[2][2]) {
    __builtin_amdgcn_s_setprio(1);
    #pragma unroll
    for (int ks = 0; ks < 2; ++ks) {
      f16x8 pa[4];
      #pragma unroll
      for (int st = 0; st < 4; ++st)
        pa[st] = *(const f16x8*)&Pbuf[cur][st][ks][lane][0];
      #pragma unroll
      for (int dt = 0; dt < 2; ++dt)
        #pragma unroll
        for (int st = 0; st < 4; ++st)
          acc[st][dt] = __builtin_amdgcn_mfma_f32_16x16x32_f16(pa[st], hb[dt][ks], acc[st][dt], 0, 0, 0);
    }
    __builtin_amdgcn_s_setprio(0);
  };

  s16x8 d0 = loadS(0);
  s16x8 d1 = loadS(1);
  s16x8 d2 = loadS(2);
  f16x8 hA[2][2], hB[2][2];
  loadH(hA, 0);
  ldsbar();                             // zld ready
  {
    s16x8 pr = expP(d0, 0);
    *(s16x8*)&Pbuf[0][mst][mks][lane][0] = pr;
  }
  ldsbar();                             // Pbuf[0] ready

  for (int ch = 0; ch < 32; ch += 2) {
    // ---- even chunk ch (reads Pbuf[0], hA) ----
    loadH(hB, ch + 1);
    {
      s16x8 prn = expP(d1, ch + 1);     // d1 holds chunk ch+1
      d1 = d2;
      if (ch + 3 < 32) d2 = loadS(ch + 3);
      mfmaStep(0, hA);
      *(s16x8*)&Pbuf[1][mst][mks][lane][0] = prn;
    }
    ldsbar();
    // ---- odd chunk ch+1 (reads Pbuf[1], hB) ----
    if (ch + 2 < 32) loadH(hA, ch + 2);
    const bool wr = (ch + 2 < 32);
    s16x8 prn2;
    if (wr) prn2 = expP(d1, ch + 2);    // d1 holds chunk ch+2
    d1 = d2;
    if (ch + 4 < 32) d2 = loadS(ch + 4);
    mfmaStep(1, hB);
    if (wr) *(s16x8*)&Pbuf[0][mst][mks][lane][0] = prn2;
    ldsbar();
  }
  // epilogue: out[b][d][s] = h[d][s] + O[s][d]; NT full-line (4 kg-lanes x 16B = 64B/line)
  #pragma unroll
  for (int st = 0; st < 4; ++st) {
    const int sb = s0t * 64 + st * 16 + kg * 4;
    #pragma unroll
    for (int dt = 0; dt < 2; ++dt) {
      const int d = w * 32 + dt * 16 + l15;
      const u16* hres = Hb + (((size_t)(w * 2 + dt) * 64 + (s0t * 2 + (st >> 1))) * 64
                        + (l15 + 16 * ((st & 1) * 2 + (kg >> 1)))) * 8 + (kg & 1) * 4;
      f32x4 o;
      o[0] = acc[st][dt][0] + h2f(hres[0]);
      o[1] = acc[st][dt][1] + h2f(hres[1]);
      o[2] = acc[st][dt][2] + h2f(hres[2]);
      o[3] = acc[st][dt][3] + h2f(hres[3]);
      __builtin_nontemporal_store(o, (f32x4*)(outp + ((size_t)(b * ND + d)) * NT + sb));
    }
  }
}

extern "C" void kernel_launch(void* const* d_in, const int* in_sizes, int n_in,
                              void* d_out, int out_size, void* d_ws, size_t ws_size,
                              hipStream_t stream) {
  const float* inF  = (const float*)d_in[0];  // [16][2048][512]
  const float* W    = (const float*)d_in[1];  // [256][256]
  const float* bias = (const float*)d_in[2];  // [256]
  float* outp = (float*)d_out;                // [16][256][2048]

  const size_t SZ = (size_t)NB * NT * ND;     // 8,388,608 elems
  u16* m16   = (u16*)d_ws;
  u16* hfrag = m16 + SZ;
  u16* aw16  = hfrag + SZ;
  float* Zarr = (float*)(aw16 + SZ);          // [B][NT] fp32 Z
  u16* Sfrag = (u16*)(Zarr + (size_t)NB * NT); // fp16 fragment-tiled S, 128 MiB
  u16* h16   = Sfrag;                          // alias: dead after kB, overwritten by k2z
  const size_t need = 3 * SZ * sizeof(u16) + (size_t)NB * NT * sizeof(float)
                    + (size_t)NB * NT * NT * sizeof(u16);   // proven present
  if (ws_size < need) return;  // visible failure (output stays poisoned)

  kA <<<dim3(NB * NT / 32), dim3(256), 0, stream>>>(inF, h16, m16, hfrag);
  kB <<<dim3(256, 2), dim3(256), 0, stream>>>(h16, W, bias, aw16);
  k2z<<<dim3(32, NB), dim3(512), 0, stream>>>(m16, aw16, Sfrag, Zarr);
  k3o<<<dim3(NT / 64, NB), dim3(512), 0, stream>>>(Sfrag, hfrag, Zarr, outp);
}

// Round 19
// 160.483 us; speedup vs baseline: 1.6002x; 1.0484x over previous
//
#include <hip/hip_runtime.h>
#include <hip/hip_bf16.h>
#include <math.h>

// AttentionLayer: B=16, T=2048, D=256
// out[b,d,s] = h[b,s,d] + sum_t h[b,t,d] * softmax_s(m[b,t,:] @ aw[b,:,:]^T)[s]
//   h = in[...,0:256] + in[...,256:512]; m = tanh(h); aw = relu(h @ W^T + b)
// Pipeline (fp16 intermediates) — r18 (best: 168.3us) + XCD-AWARE BLOCK REMAP (T1):
//   Theory: k2z's 9-round 73us equilibrium = L3 read amplification. Each batch's 32
//   blocks round-robin over all 8 XCDs -> every XCD pulls the full 16MB aw sweep into
//   its L2: 2GB L3->L2 in 73us = ~28 TB/s (invisible in FETCH, which is HBM-only).
//   Remap (1D grid, xcd = L&7, slot = L>>3; b = xcd + 8*(slot>=32), tt = slot&31)
//   puts each batch on ONE XCD -> 8x less L3 traffic; lockstep cadence unchanged.
//   kA: prep, FULL-LINE nt stores. kB: aw GEMM, LDS-transposed nt stores.
//   k2z: S GEMM -> Sfrag (through-cache) + Z; reg-staged, LDS-only barriers, setprio.
//   k3o: cooperative exp, h/S prefetch, setprio MFMA, NT full-line out stores.
// Frag layouts:
//   Sfrag[b][s/16][t/32][lane][8]: value(s,t) at lane=(s&15)+16*((t&31)>>3), j=t&7
//   hfrag[b][d/16][t/32][lane][8]: same mapping with d in place of s
// h16 aliases the first 16MB of the Sfrag region (dead after kB, overwritten by k2z).
// Refuted levers: barrier removal (r11), k2z occupancy x2 (r10,r16), NT partial-line
// stores (r8), LDS-redundancy retile (r14), T14 staging depth (r12), ldsbar-only (r13).

#define NB 16
#define NT 2048
#define ND 256

typedef __attribute__((ext_vector_type(4))) float f32x4;
typedef __attribute__((ext_vector_type(8))) short s16x8;
typedef __attribute__((ext_vector_type(4))) short s16x4;
typedef __attribute__((ext_vector_type(8))) _Float16 f16x8;
typedef unsigned short u16;

__device__ __forceinline__ u16 f2h(float x) {
  union { _Float16 h; u16 u; } v; v.h = (_Float16)x; return v.u;
}
__device__ __forceinline__ float h2f(u16 u) {
  union { u16 u; _Float16 h; } v; v.u = u; return (float)v.h;
}
__device__ __forceinline__ float tanh_fast(float x) {
  return 1.f - 2.f / (1.f + __expf(2.f * x));  // exact at tails, branch-free
}
// LDS-only barrier: waits ds ops (lgkmcnt) but NOT global/NT traffic (vmcnt floats).
__device__ __forceinline__ void ldsbar() {
  __builtin_amdgcn_sched_barrier(0);
  asm volatile("s_waitcnt lgkmcnt(0)" ::: "memory");
  __builtin_amdgcn_s_barrier();
  __builtin_amdgcn_sched_barrier(0);
}

// ---------------- kA: h = a+b; h16 [t][d], m16 [t][d], hfrag [d/16][t/32][lane][8] ----------------
__global__ __launch_bounds__(256, 8) void kA(const float* __restrict__ inF,
    u16* __restrict__ h16, u16* __restrict__ m16, u16* __restrict__ hfrag)
{
  __shared__ __attribute__((aligned(16))) u16 hld[32][264];   // [t][d] fp16 h
  const int blk = blockIdx.x;
  const int b   = blk >> 6;           // 64 blocks per batch
  const int t0  = (blk & 63) << 5;    // 32 rows
  const int tid = threadIdx.x;
  const int w    = tid >> 6;
  const int lane = tid & 63;
  const int rh   = lane >> 5;          // 0/1
  const int dseg = (lane & 31) << 3;   // 0..248 step 8
  #pragma unroll
  for (int it = 0; it < 4; ++it) {
    const int rloc = w * 8 + it * 2 + rh;
    const size_t grow = (size_t)(b * NT + t0 + rloc);
    const float* base = inF + grow * (2 * ND) + dseg;
    float4 a0 = *(const float4*)(base);
    float4 a1 = *(const float4*)(base + 4);
    float4 c0 = *(const float4*)(base + ND);
    float4 c1 = *(const float4*)(base + ND + 4);
    float hv[8] = {a0.x + c0.x, a0.y + c0.y, a0.z + c0.z, a0.w + c0.w,
                   a1.x + c1.x, a1.y + c1.y, a1.z + c1.z, a1.w + c1.w};
    s16x8 vh, vm;
    #pragma unroll
    for (int r = 0; r < 8; ++r) {
      vh[r] = (short)f2h(hv[r]);
      vm[r] = (short)f2h(tanh_fast(hv[r]));
    }
    *(s16x8*)&hld[rloc][dseg] = vh;
    __builtin_nontemporal_store(vh, (s16x8*)(h16 + grow * ND + dseg));
    __builtin_nontemporal_store(vm, (s16x8*)(m16 + grow * ND + dseg));
  }
  ldsbar();   // hld ready; NT stores keep flowing
  u16* Hb = hfrag + (size_t)b * ND * NT;
  const int ti = t0 >> 5;
  #pragma unroll
  for (int s = 0; s < 4; ++s) {
    const int slot  = tid * 4 + s;
    const int dtile = slot >> 6;
    const int lp    = slot & 63;
    const int d  = dtile * 16 + (lp & 15);
    const int tb = (lp >> 4) * 8;
    s16x8 v;
    #pragma unroll
    for (int j = 0; j < 8; ++j) v[j] = (short)hld[tb + j][d];
    __builtin_nontemporal_store(v,
        (s16x8*)(Hb + (((size_t)dtile * (NT / 32) + ti) * 64 + lp) * 8));
  }
}

// ---------------- kB: aw = relu(h @ W^T + b); LDS-transposed full-line nt stores ----------------
__global__ __launch_bounds__(256, 2) void kB(const u16* __restrict__ h16,
    const float* __restrict__ W, const float* __restrict__ bias, u16* __restrict__ aw16)
{
  __shared__ __attribute__((aligned(16))) u16 Wl[128][264];
  const int r0 = blockIdx.x << 7;
  const int e0 = blockIdx.y << 7;
  const int tid = threadIdx.x;
  #pragma unroll
  for (int rep = 0; rep < 16; ++rep) {
    const int idx = rep * 2048 + tid * 8;
    const int er = idx >> 8, col = idx & 255;
    float4 x0 = *(const float4*)(W + (size_t)(e0 + er) * ND + col);
    float4 x1 = *(const float4*)(W + (size_t)(e0 + er) * ND + col + 4);
    s16x8 v;
    v[0] = (short)f2h(x0.x); v[1] = (short)f2h(x0.y); v[2] = (short)f2h(x0.z); v[3] = (short)f2h(x0.w);
    v[4] = (short)f2h(x1.x); v[5] = (short)f2h(x1.y); v[6] = (short)f2h(x1.z); v[7] = (short)f2h(x1.w);
    *(s16x8*)&Wl[er][col] = v;
  }
  const int lane = tid & 63;
  const int w    = tid >> 6;
  const int l15  = lane & 15, kg = lane >> 4;
  float bv[8];
  #pragma unroll
  for (int et = 0; et < 8; ++et) bv[et] = bias[e0 + et * 16 + l15];
  f32x4 acc[2][8];
  #pragma unroll
  for (int rt = 0; rt < 2; ++rt)
    #pragma unroll
    for (int et = 0; et < 8; ++et) acc[rt][et] = (f32x4){0.f, 0.f, 0.f, 0.f};
  ldsbar();
  #pragma unroll
  for (int ks = 0; ks < 8; ++ks) {
    f16x8 af[2];
    #pragma unroll
    for (int rt = 0; rt < 2; ++rt)
      af[rt] = *(const f16x8*)(h16 + (size_t)(r0 + w * 32 + rt * 16 + l15) * ND + ks * 32 + kg * 8);
    #pragma unroll
    for (int et = 0; et < 8; ++et) {
      f16x8 bf = *(const f16x8*)&Wl[et * 16 + l15][ks * 32 + kg * 8];
      #pragma unroll
      for (int rt = 0; rt < 2; ++rt)
        acc[rt][et] = __builtin_amdgcn_mfma_f32_16x16x32_f16(af[rt], bf, acc[rt][et], 0, 0, 0);
    }
  }
  ldsbar();   // all waves done reading Wl
  u16 (*awt)[132] = (u16 (*)[132])(&Wl[0][0]);   // 128x132x2B = 33.8KB
  #pragma unroll
  for (int rt = 0; rt < 2; ++rt)
    #pragma unroll
    for (int et = 0; et < 8; ++et) {
      const int e_loc = et * 16 + l15;
      #pragma unroll
      for (int r = 0; r < 4; ++r) {
        const int row_loc = w * 32 + rt * 16 + kg * 4 + r;
        float v = acc[rt][et][r] + bv[et];
        awt[row_loc][e_loc] = f2h(v > 0.f ? v : 0.f);
      }
    }
  ldsbar();
  #pragma unroll
  for (int it = 0; it < 8; ++it) {
    const int rloc = it * 16 + w * 4 + (lane >> 4);
    const int sb   = (lane & 15) << 3;
    s16x8 v = *(const s16x8*)&awt[rloc][sb];
    __builtin_nontemporal_store(v, (s16x8*)(aw16 + (size_t)(r0 + rloc) * ND + e0 + sb));
  }
}

// ---------------- k2z: Sfrag (through-cache) + Z[b][t]; XCD-remapped 1D grid ----------------
__global__ __launch_bounds__(512, 4) void k2z(
    const u16* __restrict__ m16, const u16* __restrict__ aw16,
    u16* __restrict__ Sfrag, float* __restrict__ Zarr)
{
  __shared__ __attribute__((aligned(16))) u16 awch[2][64][264];  // 67.6 KB
  __shared__ float zp[2][64];
  // XCD-aware remap: batch b's 32 t-tile blocks all land on XCD (b&7).
  const int L    = blockIdx.x;       // 0..511
  const int xcd  = L & 7;
  const int slot = L >> 3;           // 0..63
  const int b    = xcd + ((slot >> 5) << 3);
  const int tt   = slot & 31;
  const int t0  = tt << 6;
  const int tid = threadIdx.x;
  const int lane = tid & 63;
  const int w    = tid >> 6;         // 0..7
  const int grp  = w >> 2;           // s 32-row half within chunk
  const int wl   = w & 3;            // t-row owner (16 rows each)
  const int l15 = lane & 15, kg = lane >> 4;
  f16x8 afr[8];
  const size_t abase = ((size_t)(b * NT + t0 + wl * 16 + l15)) * ND + kg * 8;
  #pragma unroll
  for (int ks = 0; ks < 8; ++ks) afr[ks] = *(const f16x8*)(m16 + abase + ks * 32);
  const u16* awb = aw16 + (size_t)b * NT * ND;
  u16* STb = Sfrag + (size_t)b * NT * NT;
  const int ti    = tt * 2 + (wl >> 1);
  const int lanep = l15 + 16 * ((wl & 1) * 2 + (kg >> 1));
  const int jp    = (kg & 1) * 4;
  // T14 staging: loads issued 2 steps ahead, LDS writes at step start.
  s16x8 rg[4];
  auto loadReg = [&](int step) {
    const int s0 = step << 6;
    #pragma unroll
    for (int rep = 0; rep < 4; ++rep) {
      const int idx = rep * 4096 + tid * 8;
      rg[rep] = *(const s16x8*)(awb + (size_t)(s0 + (idx >> 8)) * ND + (idx & 255));
    }
  };
  auto writeReg = [&](int buf) {
    #pragma unroll
    for (int rep = 0; rep < 4; ++rep) {
      const int idx = rep * 4096 + tid * 8;
      *(s16x8*)&awch[buf][idx >> 8][idx & 255] = rg[rep];
    }
  };
  loadReg(0); writeReg(0);     // step 0 (latency exposed once)
  loadReg(1);                  // step 1 in flight
  float zacc[4] = {0.f, 0.f, 0.f, 0.f};
  ldsbar();
  for (int step = 0; step < 32; ++step) {
    const int c = step & 1;
    if (step < 31) writeReg(c ^ 1);    // regs(step+1) -> other buffer (barrier'd)
    if (step < 30) loadReg(step + 2);  // issue next loads (full step to land)
    f32x4 accS[2];
    accS[0] = (f32x4){0.f, 0.f, 0.f, 0.f};
    accS[1] = (f32x4){0.f, 0.f, 0.f, 0.f};
    __builtin_amdgcn_s_setprio(1);
    #pragma unroll
    for (int ks = 0; ks < 8; ++ks) {
      #pragma unroll
      for (int st = 0; st < 2; ++st) {
        f16x8 bf = *(const f16x8*)&awch[c][grp * 32 + st * 16 + l15][ks * 32 + kg * 8];
        accS[st] = __builtin_amdgcn_mfma_f32_16x16x32_f16(afr[ks], bf, accS[st], 0, 0, 0);
      }
    }
    __builtin_amdgcn_s_setprio(0);
    #pragma unroll
    for (int st = 0; st < 2; ++st) {
      const int si = step * 4 + grp * 2 + st;
      s16x4 sv;
      #pragma unroll
      for (int r = 0; r < 4; ++r) sv[r] = (short)f2h(accS[st][r]);
      *(s16x4*)(STb + (((size_t)si * 64 + ti) * 64 + lanep) * 8 + jp) = sv;  // through-cache
      #pragma unroll
      for (int r = 0; r < 4; ++r) zacc[r] += __expf(accS[st][r]);
    }
    ldsbar();
  }
  #pragma unroll
  for (int r = 0; r < 4; ++r) {
    #pragma unroll
    for (int o = 1; o < 16; o <<= 1) zacc[r] += __shfl_xor(zacc[r], o, 64);
  }
  if (l15 == 0) {
    #pragma unroll
    for (int r = 0; r < 4; ++r) zp[grp][wl * 16 + kg * 4 + r] = zacc[r];
  }
  ldsbar();
  if (tid < 64)
    Zarr[(size_t)b * NT + t0 + tid] = zp[0][tid] + zp[1][tid];
}

// ---------------- k3o: cooperative exp + PV GEMM, XCD-remapped. out = h^T + O^T ----------------
__global__ __launch_bounds__(512, 4) void k3o(
    const u16* __restrict__ Sfrag, const u16* __restrict__ hfrag,
    const float* __restrict__ Zarr, float* __restrict__ outp)
{
  __shared__ __attribute__((aligned(16))) u16 Pbuf[2][4][2][64][8];  // [buf][st][ks][lane][8]
  __shared__ float zld[NT];                                          // 1/Z
  // XCD-aware remap: batch b's 32 s-tile blocks all land on XCD (b&7) -> hfrag L2 reuse.
  const int L    = blockIdx.x;       // 0..511
  const int xcd  = L & 7;
  const int slot = L >> 3;
  const int b    = xcd + ((slot >> 5) << 3);
  const int s0t  = slot & 31;        // s-tile of 64
  const int tid = threadIdx.x;
  const int lane = tid & 63;
  const int w    = tid >> 6;           // 0..7; owns d-slice [w*32, +32)
  const int l15 = lane & 15, kg = lane >> 4;
  const u16* Sb = Sfrag + (size_t)b * NT * NT;
  const u16* Hb = hfrag + (size_t)b * ND * NT;
  {
    float4 z = *(const float4*)(Zarr + (size_t)b * NT + tid * 4);
    zld[tid * 4 + 0] = 1.f / z.x;
    zld[tid * 4 + 1] = 1.f / z.y;
    zld[tid * 4 + 2] = 1.f / z.z;
    zld[tid * 4 + 3] = 1.f / z.w;
  }
  const int mst = w >> 1, mks = w & 1;   // this wave's exp duty: sub-frag (st=mst, ks=mks)
  const u16* sp = Sb + ((((size_t)(s0t * 4 + mst)) * 64 + mks) * 64 + lane) * 8;
  auto loadS = [&](int ch) -> s16x8 {
    return *(const s16x8*)(sp + (size_t)ch * 1024);   // regular: can hit L3
  };
  auto expP = [&](s16x8 v, int ch) -> s16x8 {
    const float* rzp = &zld[(ch * 2 + mks) * 32 + kg * 8];
    float4 ra = *(const float4*)rzp;
    float4 rb = *(const float4*)(rzp + 4);
    const float rv[8] = {ra.x, ra.y, ra.z, ra.w, rb.x, rb.y, rb.z, rb.w};
    s16x8 p;
    #pragma unroll
    for (int j = 0; j < 8; ++j) p[j] = (short)f2h(__expf(h2f((u16)v[j])) * rv[j]);
    return p;
  };
  auto loadH = [&](f16x8 (&dst)[2][2], int ch) {
    #pragma unroll
    for (int dt = 0; dt < 2; ++dt)
      #pragma unroll
      for (int ks = 0; ks < 2; ++ks)
        dst[dt][ks] = *(const f16x8*)(Hb + (((size_t)(w * 2 + dt) * 64 + ch * 2 + ks) * 64 + lane) * 8);
  };

  f32x4 acc[4][2];
  #pragma unroll
  for (int st = 0; st < 4; ++st) {
    acc[st][0] = (f32x4){0.f, 0.f, 0.f, 0.f};
    acc[st][1] = (f32x4){0.f, 0.f, 0.f, 0.f};
  }
  auto mfmaStep = [&](int cur, f16x8 (&hb)[2][2]) {
    __builtin_amdgcn_s_setprio(1);
    #pragma unroll
    for (int ks = 0; ks < 2; ++ks) {
      f16x8 pa[4];
      #pragma unroll
      for (int st = 0; st < 4; ++st)
        pa[st] = *(const f16x8*)&Pbuf[cur][st][ks][lane][0];
      #pragma unroll
      for (int dt = 0; dt < 2; ++dt)
        #pragma unroll
        for (int st = 0; st < 4; ++st)
          acc[st][dt] = __builtin_amdgcn_mfma_f32_16x16x32_f16(pa[st], hb[dt][ks], acc[st][dt], 0, 0, 0);
    }
    __builtin_amdgcn_s_setprio(0);
  };

  s16x8 d0 = loadS(0);
  s16x8 d1 = loadS(1);
  s16x8 d2 = loadS(2);
  f16x8 hA[2][2], hB[2][2];
  loadH(hA, 0);
  ldsbar();                             // zld ready
  {
    s16x8 pr = expP(d0, 0);
    *(s16x8*)&Pbuf[0][mst][mks][lane][0] = pr;
  }
  ldsbar();                             // Pbuf[0] ready

  for (int ch = 0; ch < 32; ch += 2) {
    // ---- even chunk ch (reads Pbuf[0], hA) ----
    loadH(hB, ch + 1);
    {
      s16x8 prn = expP(d1, ch + 1);     // d1 holds chunk ch+1
      d1 = d2;
      if (ch + 3 < 32) d2 = loadS(ch + 3);
      mfmaStep(0, hA);
      *(s16x8*)&Pbuf[1][mst][mks][lane][0] = prn;
    }
    ldsbar();
    // ---- odd chunk ch+1 (reads Pbuf[1], hB) ----
    if (ch + 2 < 32) loadH(hA, ch + 2);
    const bool wr = (ch + 2 < 32);
    s16x8 prn2;
    if (wr) prn2 = expP(d1, ch + 2);    // d1 holds chunk ch+2
    d1 = d2;
    if (ch + 4 < 32) d2 = loadS(ch + 4);
    mfmaStep(1, hB);
    if (wr) *(s16x8*)&Pbuf[0][mst][mks][lane][0] = prn2;
    ldsbar();
  }
  // epilogue: out[b][d][s] = h[d][s] + O[s][d]; NT full-line (4 kg-lanes x 16B = 64B/line)
  #pragma unroll
  for (int st = 0; st < 4; ++st) {
    const int sb = s0t * 64 + st * 16 + kg * 4;
    #pragma unroll
    for (int dt = 0; dt < 2; ++dt) {
      const int d = w * 32 + dt * 16 + l15;
      const u16* hres = Hb + (((size_t)(w * 2 + dt) * 64 + (s0t * 2 + (st >> 1))) * 64
                        + (l15 + 16 * ((st & 1) * 2 + (kg >> 1)))) * 8 + (kg & 1) * 4;
      f32x4 o;
      o[0] = acc[st][dt][0] + h2f(hres[0]);
      o[1] = acc[st][dt][1] + h2f(hres[1]);
      o[2] = acc[st][dt][2] + h2f(hres[2]);
      o[3] = acc[st][dt][3] + h2f(hres[3]);
      __builtin_nontemporal_store(o, (f32x4*)(outp + ((size_t)(b * ND + d)) * NT + sb));
    }
  }
}

extern "C" void kernel_launch(void* const* d_in, const int* in_sizes, int n_in,
                              void* d_out, int out_size, void* d_ws, size_t ws_size,
                              hipStream_t stream) {
  const float* inF  = (const float*)d_in[0];  // [16][2048][512]
  const float* W    = (const float*)d_in[1];  // [256][256]
  const float* bias = (const float*)d_in[2];  // [256]
  float* outp = (float*)d_out;                // [16][256][2048]

  const size_t SZ = (size_t)NB * NT * ND;     // 8,388,608 elems
  u16* m16   = (u16*)d_ws;
  u16* hfrag = m16 + SZ;
  u16* aw16  = hfrag + SZ;
  float* Zarr = (float*)(aw16 + SZ);          // [B][NT] fp32 Z
  u16* Sfrag = (u16*)(Zarr + (size_t)NB * NT); // fp16 fragment-tiled S, 128 MiB
  u16* h16   = Sfrag;                          // alias: dead after kB, overwritten by k2z
  const size_t need = 3 * SZ * sizeof(u16) + (size_t)NB * NT * sizeof(float)
                    + (size_t)NB * NT * NT * sizeof(u16);   // proven present
  if (ws_size < need) return;  // visible failure (output stays poisoned)

  kA <<<dim3(NB * NT / 32), dim3(256), 0, stream>>>(inF, h16, m16, hfrag);
  kB <<<dim3(256, 2), dim3(256), 0, stream>>>(h16, W, bias, aw16);
  k2z<<<dim3(512), dim3(512), 0, stream>>>(m16, aw16, Sfrag, Zarr);
  k3o<<<dim3(512), dim3(512), 0, stream>>>(Sfrag, hfrag, Zarr, outp);
}